// Round 2
// 774.636 us; speedup vs baseline: 1.1941x; 1.1941x over previous
//
#include <hip/hip_runtime.h>
#include <math.h>

#define NNODE 50000
#define NEDGE 800000
#define DINv  128
#define EDv   16
#define NHv   4
#define CHv   128
#define HCv   512
#define SLOPEv 0.2f
#define MEANBLK 512

typedef __attribute__((ext_vector_type(8))) short bf16x8;
typedef __attribute__((ext_vector_type(4))) float f32x4;
typedef __attribute__((address_space(3))) unsigned lds_u32;
typedef const __attribute__((address_space(1))) unsigned glb_u32;

__device__ __forceinline__ ushort f2b(float f) {
  unsigned u = __float_as_uint(f);
  u += 0x7FFF + ((u >> 16) & 1);
  return (ushort)(u >> 16);
}
__device__ __forceinline__ float blo(unsigned u) { return __uint_as_float(u << 16); }
__device__ __forceinline__ float bhi(unsigned u) { return __uint_as_float(u & 0xffff0000u); }

// ---------------------------------------------------------------- CSR build
__global__ void detect_kernel(const int* __restrict__ ei, int* __restrict__ flag) {
  __shared__ int bad;
  if (threadIdx.x == 0) bad = 0;
  __syncthreads();
  for (int i = threadIdx.x; i < 2048; i += 256)
    if (ei[2 * i + 1] != 0) bad = 1;
  __syncthreads();
  if (threadIdx.x == 0) flag[0] = bad ? 0 : 1;
}

__device__ __forceinline__ int load_idx(const int* __restrict__ ei, int e, int row, int wide) {
  if (wide) return ei[2 * ((size_t)row * NEDGE + e)];
  return ei[(size_t)row * NEDGE + e];
}

__global__ void count_kernel(const int* __restrict__ ei, const int* __restrict__ flag,
                             int* __restrict__ deg) {
  int e = blockIdx.x * blockDim.x + threadIdx.x;
  if (e < NEDGE) {
    int w = flag[0];
    atomicAdd(&deg[load_idx(ei, e, 1, w)], 1);
  }
}

// shfl-based single-block scan: wave-scan + wave-sum scan, 3 barriers/chunk
__global__ __launch_bounds__(1024) void scan_kernel(const int* __restrict__ deg,
                                                    int* __restrict__ row_ptr) {
  __shared__ int wsum[16];
  int tid = threadIdx.x;
  int wid = tid >> 6, lane = tid & 63;
  int carry = 0;
  for (int base = 0; base < NNODE; base += 1024) {
    int x = (base + tid < NNODE) ? deg[base + tid] : 0;
    int v = x;
#pragma unroll
    for (int off = 1; off < 64; off <<= 1) {
      int t = __shfl_up(v, off, 64);
      if (lane >= off) v += t;
    }
    if (lane == 63) wsum[wid] = v;
    __syncthreads();
    if (wid == 0) {
      int s = (lane < 16) ? wsum[lane] : 0;
#pragma unroll
      for (int off = 1; off < 16; off <<= 1) {
        int t = __shfl_up(s, off, 64);
        if (lane >= off) s += t;
      }
      if (lane < 16) wsum[lane] = s;
    }
    __syncthreads();
    int woff = wid ? wsum[wid - 1] : 0;
    if (base + tid < NNODE) row_ptr[base + tid] = carry + woff + v - x;
    carry += wsum[15];
    __syncthreads();
  }
  if (tid == 0) row_ptr[NNODE] = carry;
}

__global__ void scatter_kernel(const int* __restrict__ ei, const int* __restrict__ flag,
                               const int* __restrict__ row_ptr, int* __restrict__ cursor,
                               int* __restrict__ src_sorted, int* __restrict__ eid_sorted) {
  int e = blockIdx.x * blockDim.x + threadIdx.x;
  if (e < NEDGE) {
    int w = flag[0];
    int d = load_idx(ei, e, 1, w);
    int s = load_idx(ei, e, 0, w);
    int p = row_ptr[d] + atomicAdd(&cursor[d], 1);
    src_sorted[p] = s;
    eid_sorted[p] = e;
  }
}

// ---------------------------------------------------------------- mean(edge_features)
__global__ void mean_part_kernel(const float* __restrict__ ea, float* __restrict__ partials) {
  float acc[EDv];
#pragma unroll
  for (int d = 0; d < EDv; d++) acc[d] = 0.f;
  int stride = gridDim.x * blockDim.x;
  for (int r = blockIdx.x * blockDim.x + threadIdx.x; r < NEDGE; r += stride) {
    const float4* p = (const float4*)(ea + (size_t)r * EDv);
#pragma unroll
    for (int q = 0; q < 4; q++) {
      float4 v = p[q];
      acc[q * 4 + 0] += v.x; acc[q * 4 + 1] += v.y;
      acc[q * 4 + 2] += v.z; acc[q * 4 + 3] += v.w;
    }
  }
  __shared__ float red[4][EDv];
  int wid = threadIdx.x >> 6, lane = threadIdx.x & 63;
#pragma unroll
  for (int d = 0; d < EDv; d++) {
    float v = acc[d];
    for (int off = 32; off; off >>= 1) v += __shfl_down(v, off, 64);
    if (lane == 0) red[wid][d] = v;
  }
  __syncthreads();
  if (threadIdx.x < EDv) {
    float v = red[0][threadIdx.x] + red[1][threadIdx.x] + red[2][threadIdx.x] + red[3][threadIdx.x];
    partials[blockIdx.x * EDv + threadIdx.x] = v;
  }
}

__global__ void mean_fold_kernel(const float* __restrict__ partials, float* __restrict__ mean_sum) {
  int tid = threadIdx.x;
  int d = tid & 15, r0 = tid >> 4;
  float v = 0.f;
  for (int r = r0; r < MEANBLK; r += 16) v += partials[r * EDv + d];
  __shared__ float buf[256];
  buf[tid] = v;
  __syncthreads();
  if (r0 < 8) buf[tid] += buf[tid + 128];
  __syncthreads();
  if (r0 < 4) buf[tid] += buf[tid + 64];
  __syncthreads();
  if (r0 < 2) buf[tid] += buf[tid + 32];
  __syncthreads();
  if (r0 == 0) mean_sum[d] = buf[tid] + buf[tid + 16];
}

// ---------------------------------------------------------------- v = fold(We, a_e), loop_al_e
__global__ void vloop_kernel(const float* __restrict__ We, const float* __restrict__ a_e,
                             const float* __restrict__ mean_sum,
                             float* __restrict__ v, float* __restrict__ loop_al_e) {
  int t = threadIdx.x;  // 64 threads
  int d = t >> 2, h = t & 3;
  float s = 0.f;
  for (int c = 0; c < CHv; c++) s += We[(size_t)d * HCv + h * CHv + c] * a_e[h * CHv + c];
  v[d * 4 + h] = s;
  __syncthreads();
  if (t < NHv) {
    float acc = 0.f;
    for (int d2 = 0; d2 < EDv; d2++) acc += (mean_sum[d2] * (1.0f / NEDGE)) * v[d2 * 4 + t];
    loop_al_e[t] = acc;
  }
}

// ---------------------------------------------------------------- al_e = ea @ v   [E,4]
__global__ void ale_kernel(const float* __restrict__ ea, const float* __restrict__ v,
                           float* __restrict__ al_e) {
  __shared__ float sv[EDv * NHv];
  if (threadIdx.x < EDv * NHv) sv[threadIdx.x] = v[threadIdx.x];
  __syncthreads();
  int e = blockIdx.x * blockDim.x + threadIdx.x;
  if (e >= NEDGE) return;
  const float4* p = (const float4*)(ea + (size_t)e * EDv);
  float row[16];
  *(float4*)&row[0] = p[0]; *(float4*)&row[4] = p[1];
  *(float4*)&row[8] = p[2]; *(float4*)&row[12] = p[3];
  float o0 = 0, o1 = 0, o2 = 0, o3 = 0;
#pragma unroll
  for (int d = 0; d < 16; d++) {
    o0 += row[d] * sv[d * 4 + 0];
    o1 += row[d] * sv[d * 4 + 1];
    o2 += row[d] * sv[d * 4 + 2];
    o3 += row[d] * sv[d * 4 + 3];
  }
  ((float4*)al_e)[e] = make_float4(o0, o1, o2, o3);
}

// ---------------------------------------------------------------- ap[p] = al_src[src[p]] + al_e[eid[p]]
__global__ void apre_kernel(const int* __restrict__ src_sorted, const int* __restrict__ eid_sorted,
                            const float* __restrict__ al_src, const float* __restrict__ al_e,
                            float* __restrict__ ap) {
  int p = blockIdx.x * 256 + threadIdx.x;
  if (p >= NEDGE) return;
  int s = src_sorted[p];
  int e = eid_sorted[p];
  float4 a = ((const float4*)al_src)[s];
  float4 b = ((const float4*)al_e)[e];
  ((float4*)ap)[p] = make_float4(a.x + b.x, a.y + b.y, a.z + b.z, a.w + b.w);
}

// ---------------------------------------------------------------- conversions
__global__ void conv_bf16_kernel(const float* __restrict__ in, ushort* __restrict__ out, int n4) {
  int i = blockIdx.x * 256 + threadIdx.x;
  if (i >= n4) return;
  float4 v = ((const float4*)in)[i];
  ushort4 o;
  o.x = f2b(v.x); o.y = f2b(v.y); o.z = f2b(v.z); o.w = f2b(v.w);
  ((ushort4*)out)[i] = o;
}

// W: [K][512] f32 -> Bt: [512][K] bf16
__global__ void wt_kernel(const float* __restrict__ W, ushort* __restrict__ Bt, int K) {
  int idx = blockIdx.x * 256 + threadIdx.x;
  if (idx >= K * HCv) return;
  int k = idx >> 9, n = idx & (HCv - 1);
  Bt[(size_t)n * K + k] = f2b(W[idx]);
}

// ---------------------------------------------------------------- bf16 MFMA GEMM, bf16 output
__global__ __launch_bounds__(256) void gemm_mfma_kernel(const ushort* __restrict__ A,
                                                        const ushort* __restrict__ Bt,
                                                        ushort* __restrict__ C, int M, int K) {
  __shared__ ushort As[4][128][8];  // 8 KB
  __shared__ ushort Bs[4][128][8];  // 8 KB
  int tid = threadIdx.x;
  int wid = tid >> 6, lane = tid & 63;
  int rb = blockIdx.y * 128, cb = blockIdx.x * 128;
  int wm = (wid >> 1) * 64, wn = (wid & 1) * 64;
  int lr = lane & 15, lq = lane >> 4;

  f32x4 acc[4][4];
#pragma unroll
  for (int i = 0; i < 4; i++)
#pragma unroll
    for (int j = 0; j < 4; j++) acc[i][j] = (f32x4){0.f, 0.f, 0.f, 0.f};

  ushort* AsF = &As[0][0][0];
  ushort* BsF = &Bs[0][0][0];

  for (int k0 = 0; k0 < K; k0 += 32) {
#pragma unroll
    for (int s = 0; s < 2; s++) {
      int c = s * 256 + tid;        // chunk = kq*128 + m
      int kq = c >> 7, m = c & 127;
      int row = rb + m; if (row >= M) row = M - 1;
      const ushort* gA = A + (size_t)row * K + k0 + kq * 8;
      __builtin_amdgcn_global_load_lds((glb_u32*)gA, (lds_u32*)(AsF + (size_t)c * 8), 16, 0, 0);
    }
#pragma unroll
    for (int s = 0; s < 2; s++) {
      int c = s * 256 + tid;        // chunk = kq*128 + n
      int kq = c >> 7, n = c & 127;
      const ushort* gB = Bt + (size_t)(cb + n) * K + k0 + kq * 8;
      __builtin_amdgcn_global_load_lds((glb_u32*)gB, (lds_u32*)(BsF + (size_t)c * 8), 16, 0, 0);
    }
    __syncthreads();
    bf16x8 af[4], bfr[4];
#pragma unroll
    for (int i = 0; i < 4; i++) {
      af[i]  = *(const bf16x8*)&As[lq][wm + i * 16 + lr][0];
      bfr[i] = *(const bf16x8*)&Bs[lq][wn + i * 16 + lr][0];
    }
#pragma unroll
    for (int i = 0; i < 4; i++)
#pragma unroll
      for (int j = 0; j < 4; j++)
        acc[i][j] = __builtin_amdgcn_mfma_f32_16x16x32_bf16(af[i], bfr[j], acc[i][j], 0, 0, 0);
    __syncthreads();
  }

#pragma unroll
  for (int i = 0; i < 4; i++) {
    int rbase = rb + wm + i * 16 + lq * 4;
#pragma unroll
    for (int j = 0; j < 4; j++) {
      int col = cb + wn + j * 16 + lr;
#pragma unroll
      for (int r = 0; r < 4; r++) {
        int row = rbase + r;
        if (row < M) C[(size_t)row * HCv + col] = f2b(acc[i][j][r]);
      }
    }
  }
}

// ---------------------------------------------------------------- al_src/al_dst from bf16 h
__global__ void rowdots_kernel(const ushort* __restrict__ hb, const float* __restrict__ a_src,
                               const float* __restrict__ a_dst, float* __restrict__ al_src,
                               float* __restrict__ al_dst) {
  __shared__ float ssrc[HCv], sdst[HCv];
  int tid = threadIdx.x;  // 256
  for (int i = tid; i < HCv; i += 256) { ssrc[i] = a_src[i]; sdst[i] = a_dst[i]; }
  __syncthreads();
  int wave = tid >> 6, lane = tid & 63;
  int n = blockIdx.x * 4 + wave;
  if (n >= NNODE) return;
  const uint4* hp = (const uint4*)(hb + (size_t)n * HCv);
  uint4 u = hp[lane];  // 8 bf16: cols lane*8 .. lane*8+7
  int base = lane * 8;
  float f[8] = {blo(u.x), bhi(u.x), blo(u.y), bhi(u.y), blo(u.z), bhi(u.z), blo(u.w), bhi(u.w)};
  float s1 = 0.f, s2 = 0.f;
#pragma unroll
  for (int q = 0; q < 8; q++) {
    s1 = fmaf(f[q], ssrc[base + q], s1);
    s2 = fmaf(f[q], sdst[base + q], s2);
  }
  for (int off = 8; off; off >>= 1) {
    s1 += __shfl_down(s1, off, 64);
    s2 += __shfl_down(s2, off, 64);
  }
  if ((lane & 15) == 0) {
    int head = lane >> 4;
    al_src[n * 4 + head] = s1;
    al_dst[n * 4 + head] = s2;
  }
}

// ---------------------------------------------------------------- per-node softmax + aggregate
// ONE WAVE PER NODE. Lane l owns columns 8l..8l+7 (head = l>>4).
// Edge weights computed 16-at-a-time on the (j = lane&15, h = lane>>4) lane grid,
// broadcast via width-16 shfl. No LDS, no __syncthreads.
__global__ __launch_bounds__(256) void node_kernel(
    const ushort* __restrict__ hb, const float* __restrict__ al_src,
    const float* __restrict__ al_dst, const float* __restrict__ ap,
    const float* __restrict__ loop_al_e, const int* __restrict__ row_ptr,
    const int* __restrict__ src_sorted, const float* __restrict__ bias,
    float* __restrict__ outf, ushort* __restrict__ outb) {
  int wid = threadIdx.x >> 6, lane = threadIdx.x & 63;
  int n = blockIdx.x * 4 + wid;
  if (n >= NNODE) return;
  int base = row_ptr[n];
  int deg = row_ptr[n + 1] - base;
  int h = lane >> 4;     // head of this lane's 8 columns
  int jj = lane & 15;    // edge slot within a 16-edge chunk

  float4 aldv = *(const float4*)(al_dst + (size_t)n * 4);
  float ald[4] = {aldv.x, aldv.y, aldv.z, aldv.w};
  float alp[4];
  {
    float4 as = *(const float4*)(al_src + (size_t)n * 4);
    float aa[4] = {as.x, as.y, as.z, as.w};
#pragma unroll
    for (int q = 0; q < 4; q++) {
      float a = aa[q] + ald[q] + loop_al_e[q];
      alp[q] = a > 0.f ? a : SLOPEv * a;
    }
  }

  // ---- pass A: per-head max over edges (lane-strided), in-wave butterfly
  float mx[4] = {alp[0], alp[1], alp[2], alp[3]};
  for (int i = lane; i < deg; i += 64) {
    float4 t = ((const float4*)ap)[base + i];
    float av[4] = {t.x + ald[0], t.y + ald[1], t.z + ald[2], t.w + ald[3]};
#pragma unroll
    for (int q = 0; q < 4; q++) {
      float a = av[q] > 0.f ? av[q] : SLOPEv * av[q];
      mx[q] = fmaxf(mx[q], a);
    }
  }
#pragma unroll
  for (int q = 0; q < 4; q++) {
    float v = mx[q];
#pragma unroll
    for (int off = 32; off; off >>= 1) v = fmaxf(v, __shfl_xor(v, off, 64));
    mx[q] = v;
  }
  float mh = mx[h];
  float aldh = ald[h];

  // ---- pass B: 16-edge chunks; weights on (j,h) lane grid; gather 16 B/lane
  float acc[8];
#pragma unroll
  for (int q = 0; q < 8; q++) acc[q] = 0.f;
  float den = 0.f;

  for (int cs = 0; cs < deg; cs += 16) {
    int cl = min(16, deg - cs);
    float w = 0.f;
    int sv = 0;
    if (jj < cl) {
      int p = base + cs + jj;
      sv = src_sorted[p];
      float a = ap[(size_t)p * 4 + h] + aldh;
      a = a > 0.f ? a : SLOPEv * a;
      w = __expf(a - mh);
      den += w;
    }
    for (int j = 0; j < cl; j++) {
      int s = __shfl(sv, j, 16);
      float wj = __shfl(w, j, 16);
      uint4 u = *(const uint4*)(hb + ((size_t)s << 9) + lane * 8);
      acc[0] = fmaf(wj, blo(u.x), acc[0]);
      acc[1] = fmaf(wj, bhi(u.x), acc[1]);
      acc[2] = fmaf(wj, blo(u.y), acc[2]);
      acc[3] = fmaf(wj, bhi(u.y), acc[3]);
      acc[4] = fmaf(wj, blo(u.z), acc[4]);
      acc[5] = fmaf(wj, bhi(u.z), acc[5]);
      acc[6] = fmaf(wj, blo(u.w), acc[6]);
      acc[7] = fmaf(wj, bhi(u.w), acc[7]);
    }
  }

  // ---- self loop
  float wl = __expf(alp[h] - mh);
  {
    uint4 u = *(const uint4*)(hb + ((size_t)n << 9) + lane * 8);
    acc[0] = fmaf(wl, blo(u.x), acc[0]);
    acc[1] = fmaf(wl, bhi(u.x), acc[1]);
    acc[2] = fmaf(wl, blo(u.y), acc[2]);
    acc[3] = fmaf(wl, bhi(u.y), acc[3]);
    acc[4] = fmaf(wl, blo(u.z), acc[4]);
    acc[5] = fmaf(wl, bhi(u.z), acc[5]);
    acc[6] = fmaf(wl, blo(u.w), acc[6]);
    acc[7] = fmaf(wl, bhi(u.w), acc[7]);
  }

  // ---- denominator: reduce over the 16 j-slots within each head group
#pragma unroll
  for (int off = 8; off; off >>= 1) den += __shfl_xor(den, off, 16);
  den += wl;
  float rden = 1.f / (den + 1e-16f);

  // ---- epilogue
  const float4* bp = (const float4*)(bias + lane * 8);
  float4 b0 = bp[0], b1 = bp[1];
  float bv[8] = {b0.x, b0.y, b0.z, b0.w, b1.x, b1.y, b1.z, b1.w};
  float r[8];
#pragma unroll
  for (int q = 0; q < 8; q++) {
    float t = acc[q] * rden + bv[q];
    r[q] = t > 0.f ? t : expm1f(t);
  }
  if (outf) {
    float4* op = (float4*)(outf + (size_t)n * HCv + lane * 8);
    op[0] = make_float4(r[0], r[1], r[2], r[3]);
    op[1] = make_float4(r[4], r[5], r[6], r[7]);
  }
  if (outb) {
    uint4 o;
    o.x = (unsigned)f2b(r[0]) | ((unsigned)f2b(r[1]) << 16);
    o.y = (unsigned)f2b(r[2]) | ((unsigned)f2b(r[3]) << 16);
    o.z = (unsigned)f2b(r[4]) | ((unsigned)f2b(r[5]) << 16);
    o.w = (unsigned)f2b(r[6]) | ((unsigned)f2b(r[7]) << 16);
    ((uint4*)(outb + (size_t)n * HCv))[lane] = o;
  }
}

// ---------------------------------------------------------------- launch
static inline char* take(char*& p, size_t bytes) {
  char* r = p;
  p += (bytes + 255) & ~(size_t)255;
  return r;
}

extern "C" void kernel_launch(void* const* d_in, const int* in_sizes, int n_in,
                              void* d_out, int out_size, void* d_ws, size_t ws_size,
                              hipStream_t stream) {
  (void)in_sizes; (void)n_in; (void)out_size; (void)ws_size;
  const float* x   = (const float*)d_in[0];
  const int*   ei  = (const int*)d_in[1];
  const float* ea  = (const float*)d_in[2];
  const float* W1  = (const float*)d_in[3];
  const float* as1 = (const float*)d_in[4];
  const float* ad1 = (const float*)d_in[5];
  const float* We1 = (const float*)d_in[6];
  const float* ae1 = (const float*)d_in[7];
  const float* b1  = (const float*)d_in[8];
  const float* W2  = (const float*)d_in[9];
  const float* as2 = (const float*)d_in[10];
  const float* ad2 = (const float*)d_in[11];
  const float* We2 = (const float*)d_in[12];
  const float* ae2 = (const float*)d_in[13];
  const float* b2  = (const float*)d_in[14];
  float* out = (float*)d_out;

  char* p = (char*)d_ws;
  ushort* hb        = (ushort*)take(p, (size_t)NNODE * HCv * 2);
  float* al_src     = (float*)take(p, (size_t)NNODE * 4 * 4);
  float* al_dst     = (float*)take(p, (size_t)NNODE * 4 * 4);
  float* al_e       = (float*)take(p, (size_t)NEDGE * 4 * 4);
  float* ap         = (float*)take(p, (size_t)NEDGE * 4 * 4);
  int*   src_sorted = (int*)take(p, (size_t)NEDGE * 4);
  int*   eid_sorted = (int*)take(p, (size_t)NEDGE * 4);
  int*   row_ptr    = (int*)take(p, (size_t)(NNODE + 1) * 4);
  float* partials   = (float*)take(p, (size_t)MEANBLK * EDv * 4);
  ushort* Bt1       = (ushort*)take(p, (size_t)HCv * DINv * 2);
  ushort* Bt2       = (ushort*)take(p, (size_t)HCv * HCv * 2);
  char* zero_begin = p;
  int*   deg        = (int*)take(p, (size_t)NNODE * 4);
  int*   cursor     = (int*)take(p, (size_t)NNODE * 4);
  size_t zero_len = (size_t)(p - zero_begin);
  float* mean_sum   = (float*)take(p, 16 * 4);
  float* v          = (float*)take(p, 64 * 4);
  float* loop_ale   = (float*)take(p, 4 * 4);
  int*   flag       = (int*)take(p, 4);

  // scratch carved out of d_out (102.4 MB): xb dead after layer-1 gemm,
  // h1b dead after layer-2 gemm; final out written only by the last node_kernel.
  ushort* xb  = (ushort*)d_out;                                       // 12.8 MB
  ushort* h1b = (ushort*)((char*)d_out + (size_t)16 * 1024 * 1024);   // 51.2 MB

  hipMemsetAsync(zero_begin, 0, zero_len, stream);

  detect_kernel<<<1, 256, 0, stream>>>(ei, flag);
  count_kernel<<<(NEDGE + 255) / 256, 256, 0, stream>>>(ei, flag, deg);
  scan_kernel<<<1, 1024, 0, stream>>>(deg, row_ptr);
  scatter_kernel<<<(NEDGE + 255) / 256, 256, 0, stream>>>(ei, flag, row_ptr, cursor,
                                                          src_sorted, eid_sorted);
  mean_part_kernel<<<MEANBLK, 256, 0, stream>>>(ea, partials);
  mean_fold_kernel<<<1, 256, 0, stream>>>(partials, mean_sum);

  conv_bf16_kernel<<<(NNODE * DINv / 4 + 255) / 256, 256, 0, stream>>>(x, xb, NNODE * DINv / 4);
  wt_kernel<<<(DINv * HCv + 255) / 256, 256, 0, stream>>>(W1, Bt1, DINv);
  wt_kernel<<<(HCv * HCv + 255) / 256, 256, 0, stream>>>(W2, Bt2, HCv);

  // ---- layer 1
  vloop_kernel<<<1, 64, 0, stream>>>(We1, ae1, mean_sum, v, loop_ale);
  ale_kernel<<<(NEDGE + 255) / 256, 256, 0, stream>>>(ea, v, al_e);
  gemm_mfma_kernel<<<dim3(HCv / 128, (NNODE + 127) / 128), 256, 0, stream>>>(xb, Bt1, hb, NNODE, DINv);
  rowdots_kernel<<<(NNODE + 3) / 4, 256, 0, stream>>>(hb, as1, ad1, al_src, al_dst);
  apre_kernel<<<(NEDGE + 255) / 256, 256, 0, stream>>>(src_sorted, eid_sorted, al_src, al_e, ap);
  node_kernel<<<(NNODE + 3) / 4, 256, 0, stream>>>(hb, al_src, al_dst, ap, loop_ale, row_ptr,
                                                   src_sorted, b1, (float*)nullptr, h1b);

  // ---- layer 2
  vloop_kernel<<<1, 64, 0, stream>>>(We2, ae2, mean_sum, v, loop_ale);
  ale_kernel<<<(NEDGE + 255) / 256, 256, 0, stream>>>(ea, v, al_e);
  gemm_mfma_kernel<<<dim3(HCv / 128, (NNODE + 127) / 128), 256, 0, stream>>>(h1b, Bt2, hb, NNODE, HCv);
  rowdots_kernel<<<(NNODE + 3) / 4, 256, 0, stream>>>(hb, as2, ad2, al_src, al_dst);
  apre_kernel<<<(NEDGE + 255) / 256, 256, 0, stream>>>(src_sorted, eid_sorted, al_src, al_e, ap);
  node_kernel<<<(NNODE + 3) / 4, 256, 0, stream>>>(hb, al_src, al_dst, ap, loop_ale, row_ptr,
                                                   src_sorted, b2, out, (ushort*)nullptr);
}

// Round 3
// 734.821 us; speedup vs baseline: 1.2588x; 1.0542x over previous
//
#include <hip/hip_runtime.h>
#include <math.h>

#define NNODE 50000
#define NEDGE 800000
#define DINv  128
#define EDv   16
#define NHv   4
#define CHv   128
#define HCv   512
#define SLOPEv 0.2f
#define MEANBLK 512

typedef __attribute__((ext_vector_type(8))) short bf16x8;
typedef __attribute__((ext_vector_type(4))) float f32x4;
typedef __attribute__((address_space(3))) unsigned lds_u32;
typedef const __attribute__((address_space(1))) unsigned glb_u32;

__device__ __forceinline__ ushort f2b(float f) {
  unsigned u = __float_as_uint(f);
  u += 0x7FFF + ((u >> 16) & 1);
  return (ushort)(u >> 16);
}
__device__ __forceinline__ float blo(unsigned u) { return __uint_as_float(u << 16); }
__device__ __forceinline__ float bhi(unsigned u) { return __uint_as_float(u & 0xffff0000u); }

// ---------------------------------------------------------------- CSR build
__global__ void detect_kernel(const int* __restrict__ ei, int* __restrict__ flag) {
  __shared__ int bad;
  if (threadIdx.x == 0) bad = 0;
  __syncthreads();
  for (int i = threadIdx.x; i < 2048; i += 256)
    if (ei[2 * i + 1] != 0) bad = 1;
  __syncthreads();
  if (threadIdx.x == 0) flag[0] = bad ? 0 : 1;
}

__device__ __forceinline__ int load_idx(const int* __restrict__ ei, int e, int row, int wide) {
  if (wide) return ei[2 * ((size_t)row * NEDGE + e)];
  return ei[(size_t)row * NEDGE + e];
}

__global__ void count_kernel(const int* __restrict__ ei, const int* __restrict__ flag,
                             int* __restrict__ deg) {
  int e = blockIdx.x * blockDim.x + threadIdx.x;
  if (e < NEDGE) {
    int w = flag[0];
    atomicAdd(&deg[load_idx(ei, e, 1, w)], 1);
  }
}

// shfl-based single-block scan, 4 elements/thread (13 serial chunks)
__global__ __launch_bounds__(1024) void scan_kernel(const int* __restrict__ deg,
                                                    int* __restrict__ row_ptr) {
  __shared__ int wsum[16];
  int tid = threadIdx.x;
  int wid = tid >> 6, lane = tid & 63;
  int carry = 0;
  for (int base = 0; base < NNODE; base += 4096) {
    int idx = base + tid * 4;
    int4 x = make_int4(0, 0, 0, 0);
    if (idx < NNODE) x = *(const int4*)(deg + idx);   // NNODE % 4 == 0
    int t0 = x.x, t1 = t0 + x.y, t2 = t1 + x.z, t3 = t2 + x.w;
    int v = t3;
#pragma unroll
    for (int off = 1; off < 64; off <<= 1) {
      int t = __shfl_up(v, off, 64);
      if (lane >= off) v += t;
    }
    if (lane == 63) wsum[wid] = v;
    __syncthreads();
    if (wid == 0) {
      int s = (lane < 16) ? wsum[lane] : 0;
#pragma unroll
      for (int off = 1; off < 16; off <<= 1) {
        int t = __shfl_up(s, off, 64);
        if (lane >= off) s += t;
      }
      if (lane < 16) wsum[lane] = s;
    }
    __syncthreads();
    int woff = wid ? wsum[wid - 1] : 0;
    int excl = carry + woff + v - t3;
    if (idx < NNODE) {
      int4 o = make_int4(excl, excl + t0, excl + t1, excl + t2);
      *(int4*)(row_ptr + idx) = o;
    }
    carry += wsum[15];
    __syncthreads();
  }
  if (tid == 0) row_ptr[NNODE] = carry;
}

__global__ void scatter_kernel(const int* __restrict__ ei, const int* __restrict__ flag,
                               const int* __restrict__ row_ptr, int* __restrict__ cursor,
                               int* __restrict__ src_sorted, int* __restrict__ eid_sorted) {
  int e = blockIdx.x * blockDim.x + threadIdx.x;
  if (e < NEDGE) {
    int w = flag[0];
    int d = load_idx(ei, e, 1, w);
    int s = load_idx(ei, e, 0, w);
    int p = row_ptr[d] + atomicAdd(&cursor[d], 1);
    src_sorted[p] = s;
    eid_sorted[p] = e;
  }
}

// ---------------------------------------------------------------- mean(edge_features)
__global__ void mean_part_kernel(const float* __restrict__ ea, float* __restrict__ partials) {
  float acc[EDv];
#pragma unroll
  for (int d = 0; d < EDv; d++) acc[d] = 0.f;
  int stride = gridDim.x * blockDim.x;
  for (int r = blockIdx.x * blockDim.x + threadIdx.x; r < NEDGE; r += stride) {
    const float4* p = (const float4*)(ea + (size_t)r * EDv);
#pragma unroll
    for (int q = 0; q < 4; q++) {
      float4 v = p[q];
      acc[q * 4 + 0] += v.x; acc[q * 4 + 1] += v.y;
      acc[q * 4 + 2] += v.z; acc[q * 4 + 3] += v.w;
    }
  }
  __shared__ float red[4][EDv];
  int wid = threadIdx.x >> 6, lane = threadIdx.x & 63;
#pragma unroll
  for (int d = 0; d < EDv; d++) {
    float v = acc[d];
    for (int off = 32; off; off >>= 1) v += __shfl_down(v, off, 64);
    if (lane == 0) red[wid][d] = v;
  }
  __syncthreads();
  if (threadIdx.x < EDv) {
    float v = red[0][threadIdx.x] + red[1][threadIdx.x] + red[2][threadIdx.x] + red[3][threadIdx.x];
    partials[blockIdx.x * EDv + threadIdx.x] = v;
  }
}

__global__ void mean_fold_kernel(const float* __restrict__ partials, float* __restrict__ mean_sum) {
  int tid = threadIdx.x;
  int d = tid & 15, r0 = tid >> 4;
  float v = 0.f;
  for (int r = r0; r < MEANBLK; r += 16) v += partials[r * EDv + d];
  __shared__ float buf[256];
  buf[tid] = v;
  __syncthreads();
  if (r0 < 8) buf[tid] += buf[tid + 128];
  __syncthreads();
  if (r0 < 4) buf[tid] += buf[tid + 64];
  __syncthreads();
  if (r0 < 2) buf[tid] += buf[tid + 32];
  __syncthreads();
  if (r0 == 0) mean_sum[d] = buf[tid] + buf[tid + 16];
}

// ---------------------------------------------------------------- v = fold(We, a_e), loop_al_e
__global__ void vloop_kernel(const float* __restrict__ We, const float* __restrict__ a_e,
                             const float* __restrict__ mean_sum,
                             float* __restrict__ v, float* __restrict__ loop_al_e) {
  int t = threadIdx.x;  // 64 threads
  int d = t >> 2, h = t & 3;
  float s = 0.f;
  for (int c = 0; c < CHv; c++) s += We[(size_t)d * HCv + h * CHv + c] * a_e[h * CHv + c];
  v[d * 4 + h] = s;
  __syncthreads();
  if (t < NHv) {
    float acc = 0.f;
    for (int d2 = 0; d2 < EDv; d2++) acc += (mean_sum[d2] * (1.0f / NEDGE)) * v[d2 * 4 + t];
    loop_al_e[t] = acc;
  }
}

// ---------------------------------------------------------------- al_e = ea @ v   [E,4]
__global__ void ale_kernel(const float* __restrict__ ea, const float* __restrict__ v,
                           float* __restrict__ al_e) {
  __shared__ float sv[EDv * NHv];
  if (threadIdx.x < EDv * NHv) sv[threadIdx.x] = v[threadIdx.x];
  __syncthreads();
  int e = blockIdx.x * blockDim.x + threadIdx.x;
  if (e >= NEDGE) return;
  const float4* p = (const float4*)(ea + (size_t)e * EDv);
  float row[16];
  *(float4*)&row[0] = p[0]; *(float4*)&row[4] = p[1];
  *(float4*)&row[8] = p[2]; *(float4*)&row[12] = p[3];
  float o0 = 0, o1 = 0, o2 = 0, o3 = 0;
#pragma unroll
  for (int d = 0; d < 16; d++) {
    o0 += row[d] * sv[d * 4 + 0];
    o1 += row[d] * sv[d * 4 + 1];
    o2 += row[d] * sv[d * 4 + 2];
    o3 += row[d] * sv[d * 4 + 3];
  }
  ((float4*)al_e)[e] = make_float4(o0, o1, o2, o3);
}

// ---------------------------------------------------------------- ap[p] = al_src[src[p]] + al_e[eid[p]]
__global__ void apre_kernel(const int* __restrict__ src_sorted, const int* __restrict__ eid_sorted,
                            const float* __restrict__ al_src, const float* __restrict__ al_e,
                            float* __restrict__ ap) {
  int p = blockIdx.x * 256 + threadIdx.x;
  if (p >= NEDGE) return;
  int s = src_sorted[p];
  int e = eid_sorted[p];
  float4 a = ((const float4*)al_src)[s];
  float4 b = ((const float4*)al_e)[e];
  ((float4*)ap)[p] = make_float4(a.x + b.x, a.y + b.y, a.z + b.z, a.w + b.w);
}

// ---------------------------------------------------------------- conversions
__global__ void conv_bf16_kernel(const float* __restrict__ in, ushort* __restrict__ out, int n4) {
  int i = blockIdx.x * 256 + threadIdx.x;
  if (i >= n4) return;
  float4 v = ((const float4*)in)[i];
  ushort4 o;
  o.x = f2b(v.x); o.y = f2b(v.y); o.z = f2b(v.z); o.w = f2b(v.w);
  ((ushort4*)out)[i] = o;
}

// W: [K][512] f32 -> Bt: [512][K] bf16
__global__ void wt_kernel(const float* __restrict__ W, ushort* __restrict__ Bt, int K) {
  int idx = blockIdx.x * 256 + threadIdx.x;
  if (idx >= K * HCv) return;
  int k = idx >> 9, n = idx & (HCv - 1);
  Bt[(size_t)n * K + k] = f2b(W[idx]);
}

// ---------------------------------------------------------------- bf16 MFMA GEMM + fused rowdots
// Each 128-col block covers exactly one head (C=128); computes complete
// al_src/al_dst for its 128 rows via in-register dot + width-16 shfl reduce.
// XCD-chunked block swizzle: 4 col-blocks sharing an A band land on one XCD.
__global__ __launch_bounds__(256) void gemm_mfma_kernel(const ushort* __restrict__ A,
                                                        const ushort* __restrict__ Bt,
                                                        ushort* __restrict__ C, int M, int K,
                                                        const float* __restrict__ a_src,
                                                        const float* __restrict__ a_dst,
                                                        float* __restrict__ al_src,
                                                        float* __restrict__ al_dst) {
  __shared__ ushort As[4][128][8];  // 8 KB
  __shared__ ushort Bs[4][128][8];  // 8 KB
  __shared__ float ssa[128], ssd[128];
  __shared__ float rsum[2][128][2];
  int tid = threadIdx.x;
  int wid = tid >> 6, lane = tid & 63;

  // bijective XCD-chunk swizzle over gridDim.x * gridDim.y blocks (x fastest)
  int nblk = gridDim.x * gridDim.y;
  int j = blockIdx.y * gridDim.x + blockIdx.x;
  int q = nblk >> 3, rem = nblk & 7;
  int xcd = j & 7, idx = j >> 3;
  int d = (xcd < rem) ? xcd * (q + 1) + idx : rem * (q + 1) + (xcd - rem) * q + idx;
  int rb = (d >> 2) * 128, cb = (d & 3) * 128;
  int hblk = cb >> 7;

  int wm = (wid >> 1) * 64, wn = (wid & 1) * 64;
  int lr = lane & 15, lq = lane >> 4;

  if (tid < 128) { ssa[tid] = a_src[cb + tid]; ssd[tid] = a_dst[cb + tid]; }

  f32x4 acc[4][4];
#pragma unroll
  for (int i = 0; i < 4; i++)
#pragma unroll
    for (int jx = 0; jx < 4; jx++) acc[i][jx] = (f32x4){0.f, 0.f, 0.f, 0.f};

  ushort* AsF = &As[0][0][0];
  ushort* BsF = &Bs[0][0][0];

  for (int k0 = 0; k0 < K; k0 += 32) {
#pragma unroll
    for (int s = 0; s < 2; s++) {
      int c = s * 256 + tid;        // chunk = kq*128 + m
      int kq = c >> 7, m = c & 127;
      int row = rb + m; if (row >= M) row = M - 1;
      const ushort* gA = A + (size_t)row * K + k0 + kq * 8;
      __builtin_amdgcn_global_load_lds((glb_u32*)gA, (lds_u32*)(AsF + (size_t)c * 8), 16, 0, 0);
    }
#pragma unroll
    for (int s = 0; s < 2; s++) {
      int c = s * 256 + tid;        // chunk = kq*128 + n
      int kq = c >> 7, n = c & 127;
      const ushort* gB = Bt + (size_t)(cb + n) * K + k0 + kq * 8;
      __builtin_amdgcn_global_load_lds((glb_u32*)gB, (lds_u32*)(BsF + (size_t)c * 8), 16, 0, 0);
    }
    __syncthreads();
    bf16x8 af[4], bfr[4];
#pragma unroll
    for (int i = 0; i < 4; i++) {
      af[i]  = *(const bf16x8*)&As[lq][wm + i * 16 + lr][0];
      bfr[i] = *(const bf16x8*)&Bs[lq][wn + i * 16 + lr][0];
    }
#pragma unroll
    for (int i = 0; i < 4; i++)
#pragma unroll
      for (int jx = 0; jx < 4; jx++)
        acc[i][jx] = __builtin_amdgcn_mfma_f32_16x16x32_bf16(af[i], bfr[jx], acc[i][jx], 0, 0, 0);
    __syncthreads();
  }

  // C store (bf16)
#pragma unroll
  for (int i = 0; i < 4; i++) {
    int rbase = rb + wm + i * 16 + lq * 4;
#pragma unroll
    for (int jx = 0; jx < 4; jx++) {
      int col = cb + wn + jx * 16 + lr;
#pragma unroll
      for (int r = 0; r < 4; r++) {
        int row = rbase + r;
        if (row < M) C[(size_t)row * HCv + col] = f2b(acc[i][jx][r]);
      }
    }
  }

  // fused rowdots epilogue
  float sa[4], sd[4];
#pragma unroll
  for (int jx = 0; jx < 4; jx++) {
    int c = wn + jx * 16 + lr;
    sa[jx] = ssa[c]; sd[jx] = ssd[c];
  }
#pragma unroll
  for (int i = 0; i < 4; i++) {
#pragma unroll
    for (int r = 0; r < 4; r++) {
      float s1 = 0.f, s2 = 0.f;
#pragma unroll
      for (int jx = 0; jx < 4; jx++) {
        s1 = fmaf(acc[i][jx][r], sa[jx], s1);
        s2 = fmaf(acc[i][jx][r], sd[jx], s2);
      }
#pragma unroll
      for (int off = 1; off < 16; off <<= 1) {
        s1 += __shfl_xor(s1, off, 16);
        s2 += __shfl_xor(s2, off, 16);
      }
      if (lr == 0) {
        int row = wm + i * 16 + lq * 4 + r;
        rsum[0][row][wn >> 6] = s1;
        rsum[1][row][wn >> 6] = s2;
      }
    }
  }
  __syncthreads();
  if (tid < 128) {
    int row = rb + tid;
    if (row < M) {
      al_src[(size_t)row * 4 + hblk] = rsum[0][tid][0] + rsum[0][tid][1];
      al_dst[(size_t)row * 4 + hblk] = rsum[1][tid][0] + rsum[1][tid][1];
    }
  }
}

// ---------------------------------------------------------------- per-node softmax + aggregate
// ONE WAVE PER NODE, no max pass (|alpha| ~ O(3) => exp safe in f32).
// Lane l owns columns 8l..8l+7 (head = l>>4). Weights for 16 edges computed
// on the (j = lane&15, h = lane>>4) grid; gather batched 4-deep for MLP.
__device__ __forceinline__ void fma8(float* acc, float w, uint4 u) {
  acc[0] = fmaf(w, blo(u.x), acc[0]);
  acc[1] = fmaf(w, bhi(u.x), acc[1]);
  acc[2] = fmaf(w, blo(u.y), acc[2]);
  acc[3] = fmaf(w, bhi(u.y), acc[3]);
  acc[4] = fmaf(w, blo(u.z), acc[4]);
  acc[5] = fmaf(w, bhi(u.z), acc[5]);
  acc[6] = fmaf(w, blo(u.w), acc[6]);
  acc[7] = fmaf(w, bhi(u.w), acc[7]);
}

__global__ __launch_bounds__(256) void node_kernel(
    const ushort* __restrict__ hb, const float* __restrict__ al_src,
    const float* __restrict__ al_dst, const float* __restrict__ ap,
    const float* __restrict__ loop_al_e, const int* __restrict__ row_ptr,
    const int* __restrict__ src_sorted, const float* __restrict__ bias,
    float* __restrict__ outf, ushort* __restrict__ outb) {
  int wid = threadIdx.x >> 6, lane = threadIdx.x & 63;
  int n = blockIdx.x * 4 + wid;
  if (n >= NNODE) return;
  int base = row_ptr[n];
  int deg = row_ptr[n + 1] - base;
  int h = lane >> 4;     // head of this lane's 8 columns
  int jj = lane & 15;    // edge slot within a 16-edge chunk

  float aldh = al_dst[(size_t)n * 4 + h];
  float a0 = al_src[(size_t)n * 4 + h] + aldh + loop_al_e[h];
  float alph = a0 > 0.f ? a0 : SLOPEv * a0;
  float wl = __expf(alph);

  // self row, issued early
  uint4 uself = *((const uint4*)(hb + ((size_t)n << 9)) + lane);

  float acc[8];
#pragma unroll
  for (int q = 0; q < 8; q++) acc[q] = 0.f;
  float den = 0.f;

  for (int cs = 0; cs < deg; cs += 16) {
    int cl = min(16, deg - cs);
    float w = 0.f;
    int sv = 0;
    if (jj < cl) {
      int p = base + cs + jj;
      sv = src_sorted[p];
      float a = ap[(size_t)p * 4 + h] + aldh;
      a = a > 0.f ? a : SLOPEv * a;
      w = __expf(a);
      den += w;
    }
    int cl4 = (cl + 3) & ~3;   // lanes j>=cl have w=0, sv=0 (harmless hot row-0 load)
    for (int j0 = 0; j0 < cl4; j0 += 4) {
      int s0 = __shfl(sv, j0 + 0, 16);
      int s1 = __shfl(sv, j0 + 1, 16);
      int s2 = __shfl(sv, j0 + 2, 16);
      int s3 = __shfl(sv, j0 + 3, 16);
      float w0 = __shfl(w, j0 + 0, 16);
      float w1 = __shfl(w, j0 + 1, 16);
      float w2 = __shfl(w, j0 + 2, 16);
      float w3 = __shfl(w, j0 + 3, 16);
      uint4 u0 = *((const uint4*)(hb + ((size_t)s0 << 9)) + lane);
      uint4 u1 = *((const uint4*)(hb + ((size_t)s1 << 9)) + lane);
      uint4 u2 = *((const uint4*)(hb + ((size_t)s2 << 9)) + lane);
      uint4 u3 = *((const uint4*)(hb + ((size_t)s3 << 9)) + lane);
      fma8(acc, w0, u0);
      fma8(acc, w1, u1);
      fma8(acc, w2, u2);
      fma8(acc, w3, u3);
    }
  }

  // self loop
  fma8(acc, wl, uself);

  // denominator: reduce over the 16 j-slots within each head group
#pragma unroll
  for (int off = 8; off; off >>= 1) den += __shfl_xor(den, off, 16);
  den += wl;
  float rden = 1.f / (den + 1e-16f);

  // epilogue
  const float4* bp = (const float4*)(bias + lane * 8);
  float4 b0 = bp[0], b1 = bp[1];
  float bv[8] = {b0.x, b0.y, b0.z, b0.w, b1.x, b1.y, b1.z, b1.w};
  float r[8];
#pragma unroll
  for (int q = 0; q < 8; q++) {
    float t = acc[q] * rden + bv[q];
    r[q] = t > 0.f ? t : expm1f(t);
  }
  if (outf) {
    float4* op = (float4*)(outf + (size_t)n * HCv + lane * 8);
    op[0] = make_float4(r[0], r[1], r[2], r[3]);
    op[1] = make_float4(r[4], r[5], r[6], r[7]);
  }
  if (outb) {
    uint4 o;
    o.x = (unsigned)f2b(r[0]) | ((unsigned)f2b(r[1]) << 16);
    o.y = (unsigned)f2b(r[2]) | ((unsigned)f2b(r[3]) << 16);
    o.z = (unsigned)f2b(r[4]) | ((unsigned)f2b(r[5]) << 16);
    o.w = (unsigned)f2b(r[6]) | ((unsigned)f2b(r[7]) << 16);
    ((uint4*)(outb + (size_t)n * HCv))[lane] = o;
  }
}

// ---------------------------------------------------------------- launch
static inline char* take(char*& p, size_t bytes) {
  char* r = p;
  p += (bytes + 255) & ~(size_t)255;
  return r;
}

extern "C" void kernel_launch(void* const* d_in, const int* in_sizes, int n_in,
                              void* d_out, int out_size, void* d_ws, size_t ws_size,
                              hipStream_t stream) {
  (void)in_sizes; (void)n_in; (void)out_size; (void)ws_size;
  const float* x   = (const float*)d_in[0];
  const int*   ei  = (const int*)d_in[1];
  const float* ea  = (const float*)d_in[2];
  const float* W1  = (const float*)d_in[3];
  const float* as1 = (const float*)d_in[4];
  const float* ad1 = (const float*)d_in[5];
  const float* We1 = (const float*)d_in[6];
  const float* ae1 = (const float*)d_in[7];
  const float* b1  = (const float*)d_in[8];
  const float* W2  = (const float*)d_in[9];
  const float* as2 = (const float*)d_in[10];
  const float* ad2 = (const float*)d_in[11];
  const float* We2 = (const float*)d_in[12];
  const float* ae2 = (const float*)d_in[13];
  const float* b2  = (const float*)d_in[14];
  float* out = (float*)d_out;

  char* p = (char*)d_ws;
  ushort* hb        = (ushort*)take(p, (size_t)NNODE * HCv * 2);
  float* al_src     = (float*)take(p, (size_t)NNODE * 4 * 4);
  float* al_dst     = (float*)take(p, (size_t)NNODE * 4 * 4);
  float* al_e       = (float*)take(p, (size_t)NEDGE * 4 * 4);
  float* ap         = (float*)take(p, (size_t)NEDGE * 4 * 4);
  int*   src_sorted = (int*)take(p, (size_t)NEDGE * 4);
  int*   eid_sorted = (int*)take(p, (size_t)NEDGE * 4);
  int*   row_ptr    = (int*)take(p, (size_t)(NNODE + 1) * 4);
  float* partials   = (float*)take(p, (size_t)MEANBLK * EDv * 4);
  ushort* Bt1       = (ushort*)take(p, (size_t)HCv * DINv * 2);
  ushort* Bt2       = (ushort*)take(p, (size_t)HCv * HCv * 2);
  char* zero_begin = p;
  int*   deg        = (int*)take(p, (size_t)NNODE * 4);
  int*   cursor     = (int*)take(p, (size_t)NNODE * 4);
  size_t zero_len = (size_t)(p - zero_begin);
  float* mean_sum   = (float*)take(p, 16 * 4);
  float* v          = (float*)take(p, 64 * 4);
  float* loop_ale   = (float*)take(p, 4 * 4);
  int*   flag       = (int*)take(p, 4);

  // scratch carved out of d_out (102.4 MB): xb dead after layer-1 gemm,
  // h1b dead after layer-2 gemm; final out written only by the last node_kernel.
  ushort* xb  = (ushort*)d_out;                                       // 12.8 MB
  ushort* h1b = (ushort*)((char*)d_out + (size_t)16 * 1024 * 1024);   // 51.2 MB

  hipMemsetAsync(zero_begin, 0, zero_len, stream);

  detect_kernel<<<1, 256, 0, stream>>>(ei, flag);
  count_kernel<<<(NEDGE + 255) / 256, 256, 0, stream>>>(ei, flag, deg);
  scan_kernel<<<1, 1024, 0, stream>>>(deg, row_ptr);
  scatter_kernel<<<(NEDGE + 255) / 256, 256, 0, stream>>>(ei, flag, row_ptr, cursor,
                                                          src_sorted, eid_sorted);
  mean_part_kernel<<<MEANBLK, 256, 0, stream>>>(ea, partials);
  mean_fold_kernel<<<1, 256, 0, stream>>>(partials, mean_sum);

  conv_bf16_kernel<<<(NNODE * DINv / 4 + 255) / 256, 256, 0, stream>>>(x, xb, NNODE * DINv / 4);
  wt_kernel<<<(DINv * HCv + 255) / 256, 256, 0, stream>>>(W1, Bt1, DINv);
  wt_kernel<<<(HCv * HCv + 255) / 256, 256, 0, stream>>>(W2, Bt2, HCv);

  // ---- layer 1
  vloop_kernel<<<1, 64, 0, stream>>>(We1, ae1, mean_sum, v, loop_ale);
  ale_kernel<<<(NEDGE + 255) / 256, 256, 0, stream>>>(ea, v, al_e);
  gemm_mfma_kernel<<<dim3(HCv / 128, (NNODE + 127) / 128), 256, 0, stream>>>(
      xb, Bt1, hb, NNODE, DINv, as1, ad1, al_src, al_dst);
  apre_kernel<<<(NEDGE + 255) / 256, 256, 0, stream>>>(src_sorted, eid_sorted, al_src, al_e, ap);
  node_kernel<<<(NNODE + 3) / 4, 256, 0, stream>>>(hb, al_src, al_dst, ap, loop_ale, row_ptr,
                                                   src_sorted, b1, (float*)nullptr, h1b);

  // ---- layer 2
  vloop_kernel<<<1, 64, 0, stream>>>(We2, ae2, mean_sum, v, loop_ale);
  ale_kernel<<<(NEDGE + 255) / 256, 256, 0, stream>>>(ea, v, al_e);
  gemm_mfma_kernel<<<dim3(HCv / 128, (NNODE + 127) / 128), 256, 0, stream>>>(
      h1b, Bt2, hb, NNODE, HCv, as2, ad2, al_src, al_dst);
  apre_kernel<<<(NEDGE + 255) / 256, 256, 0, stream>>>(src_sorted, eid_sorted, al_src, al_e, ap);
  node_kernel<<<(NNODE + 3) / 4, 256, 0, stream>>>(hb, al_src, al_dst, ap, loop_ale, row_ptr,
                                                   src_sorted, b2, out, (ushort*)nullptr);
}